// Round 3
// baseline (588.245 us; speedup 1.0000x reference)
//
#include <hip/hip_runtime.h>

// LogicGatedSNN: fused, 2-rows-per-wave software pipeline (R3).
//
// R2 post-mortem: fusion only moved total 589->578, so fixed harness cost
// ~= 430-445us and our kernel ~= 135-150us vs a 768 MiB / 6.5 TB/s ~= 118us
// floor. Remaining theory: lockstep phases (pure-read phase, then RMW phase)
// + zero memory in flight during the butterfly. Fix: each wave owns TWO
// rows and pipelines: dot(r0) -> [dot(r1) || traceRMW(r0)] -> traceRMW(r1).
// Middle phase issues 3 concurrent streams per wave (syn read, trace read,
// trace write) -> smoother chip-wide read/write mix, 2x per-wave MLP.
// If this is neutral, the kernel is at its HBM floor (declare roofline).

#define IN_F 8192
#define OUT_F 8192
#define BLOCK 256
#define ROW4 (IN_F / 4)          // 2048 float4 per row
#define CHUNKS (ROW4 / 64)       // 32 float4 iterations per lane per row

typedef float f32x4 __attribute__((ext_vector_type(4)));

__device__ __forceinline__ float dot_step(const f32x4 s, const f32x4 xv) {
    float a = 0.0f;
    a += (s[0] > 50.0f) ? xv[0] : 0.0f;
    a += (s[1] > 50.0f) ? xv[1] : 0.0f;
    a += (s[2] > 50.0f) ? xv[2] : 0.0f;
    a += (s[3] > 50.0f) ? xv[3] : 0.0f;
    return a;
}

__device__ __forceinline__ f32x4 trace_step(const f32x4 t, const f32x4 xv,
                                            const float spike) {
    f32x4 o;
    o[0] = fminf(fmaxf(t[0] * 0.8f + spike * xv[0], 0.0f), 5.0f);
    o[1] = fminf(fmaxf(t[1] * 0.8f + spike * xv[1], 0.0f), 5.0f);
    o[2] = fminf(fmaxf(t[2] * 0.8f + spike * xv[2], 0.0f), 5.0f);
    o[3] = fminf(fmaxf(t[3] * 0.8f + spike * xv[3], 0.0f), 5.0f);
    return o;
}

__global__ __launch_bounds__(BLOCK) void snn_fused_kernel(
    const f32x4* __restrict__ x4,      // spike_input [IN_F/4]
    const float* __restrict__ syn,     // synapse_states [OUT_F, IN_F]
    const float* __restrict__ mem,     // membrane_potential [OUT_F]
    const float* __restrict__ thr,     // adaptive_threshold [OUT_F]
    const float* __restrict__ refr,    // refractory_period [OUT_F]
    const f32x4* __restrict__ tr4,     // eligibility_trace [OUT_F * IN_F/4]
    float* __restrict__ out_spikes,
    float* __restrict__ out_mem,
    float* __restrict__ out_refr,
    f32x4* __restrict__ otr4)          // out_trace [OUT_F * IN_F/4]
{
    const int wave = threadIdx.x >> 6;            // 0..3
    const int lane = threadIdx.x & 63;
    const int r0   = (blockIdx.x << 3) + (wave << 1);  // 8 rows per block
    const int r1   = r0 + 1;

    const f32x4* __restrict__ synA = (const f32x4*)syn + (size_t)r0 * ROW4;
    const f32x4* __restrict__ synB = (const f32x4*)syn + (size_t)r1 * ROW4;
    const f32x4* __restrict__ trA  = tr4  + (size_t)r0 * ROW4;
    const f32x4* __restrict__ trB  = tr4  + (size_t)r1 * ROW4;
    f32x4* __restrict__ otrA       = otr4 + (size_t)r0 * ROW4;
    f32x4* __restrict__ otrB       = otr4 + (size_t)r1 * ROW4;

    // Row scalars (wave-uniform broadcast loads, latency hidden by streams).
    const float rA = refr[r0], mA = mem[r0], tA = thr[r0];
    const float rB = refr[r1], mB = mem[r1], tB = thr[r1];

    // ---- Phase A: dot(r0) ----
    float acc0 = 0.0f;
    #pragma unroll 8
    for (int it = 0; it < CHUNKS; ++it) {
        const int idx = (it << 6) + lane;
        acc0 += dot_step(__builtin_nontemporal_load(&synA[idx]), x4[idx]);
    }
    #pragma unroll
    for (int off = 32; off > 0; off >>= 1)
        acc0 += __shfl_xor(acc0, off, 64);

    const float v0     = mA * 0.5f + acc0 * (1.0f - rA * 0.5f);
    const float spike0 = (v0 >= tA) ? 1.0f : 0.0f;
    if (lane == 0) {
        out_spikes[r0] = spike0;
        out_mem[r0]    = v0 * (1.0f - spike0);
        out_refr[r0]   = fminf(fmaxf(rA + spike0 - 0.1f, 0.0f), 1.0f);
    }

    // ---- Phase B: dot(r1) || traceRMW(r0) — 3 concurrent streams ----
    float acc1 = 0.0f;
    #pragma unroll 4
    for (int it = 0; it < CHUNKS; ++it) {
        const int idx = (it << 6) + lane;
        const f32x4 xv = x4[idx];
        const f32x4 s  = __builtin_nontemporal_load(&synB[idx]);
        const f32x4 t  = __builtin_nontemporal_load(&trA[idx]);
        acc1 += dot_step(s, xv);
        __builtin_nontemporal_store(trace_step(t, xv, spike0), &otrA[idx]);
    }
    #pragma unroll
    for (int off = 32; off > 0; off >>= 1)
        acc1 += __shfl_xor(acc1, off, 64);

    const float v1     = mB * 0.5f + acc1 * (1.0f - rB * 0.5f);
    const float spike1 = (v1 >= tB) ? 1.0f : 0.0f;
    if (lane == 0) {
        out_spikes[r1] = spike1;
        out_mem[r1]    = v1 * (1.0f - spike1);
        out_refr[r1]   = fminf(fmaxf(rB + spike1 - 0.1f, 0.0f), 1.0f);
    }

    // ---- Phase C: traceRMW(r1) ----
    #pragma unroll 8
    for (int it = 0; it < CHUNKS; ++it) {
        const int idx = (it << 6) + lane;
        const f32x4 t  = __builtin_nontemporal_load(&trB[idx]);
        __builtin_nontemporal_store(trace_step(t, x4[idx], spike1), &otrB[idx]);
    }
}

extern "C" void kernel_launch(void* const* d_in, const int* in_sizes, int n_in,
                              void* d_out, int out_size, void* d_ws, size_t ws_size,
                              hipStream_t stream) {
    const float* x_in  = (const float*)d_in[0];  // spike_input
    const float* syn   = (const float*)d_in[1];  // synapse_states
    const float* mem   = (const float*)d_in[2];  // membrane_potential
    const float* thr   = (const float*)d_in[3];  // adaptive_threshold
    const float* trace = (const float*)d_in[4];  // eligibility_trace
    const float* refr  = (const float*)d_in[5];  // refractory_period

    float* out = (float*)d_out;
    float* out_spikes = out;                                     // [8192]
    float* out_mem    = out + OUT_F;                             // [8192]
    float* out_trace  = out + 2 * OUT_F;                         // [8192^2]
    float* out_refr   = out + 2 * OUT_F + (size_t)OUT_F * IN_F;  // [8192]

    snn_fused_kernel<<<OUT_F / 8, BLOCK, 0, stream>>>(
        (const f32x4*)x_in, syn, mem, thr, refr,
        (const f32x4*)trace,
        out_spikes, out_mem, out_refr,
        (f32x4*)out_trace);
}

// Round 4
// 575.507 us; speedup vs baseline: 1.0221x; 1.0221x over previous
//
#include <hip/hip_runtime.h>

// LogicGatedSNN: fused 1-row-per-wave + trace-in register prefetch (R4).
//
// R3 post-mortem: 2-row pipeline halved grid -> 41% occupancy -> 163us
// (vs R2's 153us at full occupancy). Revert to 1 row/wave, 2048 blocks.
// R4 lever: trace-IN loads don't depend on spike (only stores do). Issue
// the first 16 trace-in f32x4 loads BEFORE the syn stream and hold them in
// registers; vmcnt in-order semantics mean they've landed when the dot
// drain completes -> phase 2 starts with zero cold-start and the wave's
// memory queue never empties across the phase transition.
// ~110 VGPR -> still 8 waves/SIMD (full occupancy).
// Floor: ~805 MB @ 6.5 TB/s ~= 124us for our dispatch; harness fixed cost
// ~425us. If total stays ~578, we're at the mixed-stream HBM ceiling.

#define IN_F 8192
#define OUT_F 8192
#define BLOCK 256
#define ROW4 (IN_F / 4)          // 2048 float4 per row
#define CHUNKS (ROW4 / 64)       // 32 float4 iterations per lane per row
#define PF 16                    // trace-in quads prefetched into registers

typedef float f32x4 __attribute__((ext_vector_type(4)));

__device__ __forceinline__ float dot_step(const f32x4 s, const f32x4 xv) {
    float a = 0.0f;
    a += (s[0] > 50.0f) ? xv[0] : 0.0f;
    a += (s[1] > 50.0f) ? xv[1] : 0.0f;
    a += (s[2] > 50.0f) ? xv[2] : 0.0f;
    a += (s[3] > 50.0f) ? xv[3] : 0.0f;
    return a;
}

__device__ __forceinline__ f32x4 trace_step(const f32x4 t, const f32x4 xv,
                                            const float spike) {
    f32x4 o;
    o[0] = fminf(fmaxf(t[0] * 0.8f + spike * xv[0], 0.0f), 5.0f);
    o[1] = fminf(fmaxf(t[1] * 0.8f + spike * xv[1], 0.0f), 5.0f);
    o[2] = fminf(fmaxf(t[2] * 0.8f + spike * xv[2], 0.0f), 5.0f);
    o[3] = fminf(fmaxf(t[3] * 0.8f + spike * xv[3], 0.0f), 5.0f);
    return o;
}

__global__ __launch_bounds__(BLOCK) void snn_fused_kernel(
    const f32x4* __restrict__ x4,      // spike_input [IN_F/4]
    const float* __restrict__ syn,     // synapse_states [OUT_F, IN_F]
    const float* __restrict__ mem,     // membrane_potential [OUT_F]
    const float* __restrict__ thr,     // adaptive_threshold [OUT_F]
    const float* __restrict__ refr,    // refractory_period [OUT_F]
    const f32x4* __restrict__ tr4,     // eligibility_trace [OUT_F * IN_F/4]
    float* __restrict__ out_spikes,
    float* __restrict__ out_mem,
    float* __restrict__ out_refr,
    f32x4* __restrict__ otr4)          // out_trace [OUT_F * IN_F/4]
{
    const int wave = threadIdx.x >> 6;           // 0..3
    const int lane = threadIdx.x & 63;
    const int row  = (blockIdx.x << 2) + wave;

    const size_t base4 = (size_t)row * ROW4;
    const f32x4* __restrict__ syn4 = (const f32x4*)syn + base4;
    const f32x4* __restrict__ trR  = tr4  + base4;
    f32x4* __restrict__ otrR       = otr4 + base4;

    // Row scalars (wave-uniform broadcast loads).
    const float r_in = refr[row];
    const float m_in = mem[row];
    const float t_in = thr[row];

    // ---- Prefetch: first PF trace-in quads into registers (no spike dep).
    // Issued before the syn stream; in-order vmcnt guarantees they land
    // by the time the dot drain completes.
    f32x4 tbuf[PF];
    #pragma unroll
    for (int it = 0; it < PF; ++it) {
        tbuf[it] = __builtin_nontemporal_load(&trR[(it << 6) + lane]);
    }

    // ---- Phase 1: current = (syn > 50) . x  (read stream) ----
    float acc = 0.0f;
    #pragma unroll 8
    for (int it = 0; it < CHUNKS; ++it) {
        const int idx = (it << 6) + lane;
        acc += dot_step(__builtin_nontemporal_load(&syn4[idx]), x4[idx]);
    }

    // 64-lane butterfly: every lane ends with the full row sum (exact:
    // operands are 0/1 counts, integer-valued in fp32).
    #pragma unroll
    for (int off = 32; off > 0; off >>= 1)
        acc += __shfl_xor(acc, off, 64);

    // ---- LIF scalars (all lanes compute identically; lane 0 writes) ----
    const float v     = m_in * 0.5f + acc * (1.0f - r_in * 0.5f);
    const float spike = (v >= t_in) ? 1.0f : 0.0f;
    if (lane == 0) {
        out_spikes[row] = spike;
        out_mem[row]    = v * (1.0f - spike);
        out_refr[row]   = fminf(fmaxf(r_in + spike - 0.1f, 0.0f), 1.0f);
    }

    // ---- Phase 2a: consume prefetched quads (zero memory stall) ----
    #pragma unroll
    for (int it = 0; it < PF; ++it) {
        const int idx = (it << 6) + lane;
        __builtin_nontemporal_store(trace_step(tbuf[it], x4[idx], spike),
                                    &otrR[idx]);
    }

    // ---- Phase 2b: stream the remaining trace RMW ----
    #pragma unroll 8
    for (int it = PF; it < CHUNKS; ++it) {
        const int idx = (it << 6) + lane;
        const f32x4 t = __builtin_nontemporal_load(&trR[idx]);
        __builtin_nontemporal_store(trace_step(t, x4[idx], spike),
                                    &otrR[idx]);
    }
}

extern "C" void kernel_launch(void* const* d_in, const int* in_sizes, int n_in,
                              void* d_out, int out_size, void* d_ws, size_t ws_size,
                              hipStream_t stream) {
    const float* x_in  = (const float*)d_in[0];  // spike_input
    const float* syn   = (const float*)d_in[1];  // synapse_states
    const float* mem   = (const float*)d_in[2];  // membrane_potential
    const float* thr   = (const float*)d_in[3];  // adaptive_threshold
    const float* trace = (const float*)d_in[4];  // eligibility_trace
    const float* refr  = (const float*)d_in[5];  // refractory_period

    float* out = (float*)d_out;
    float* out_spikes = out;                                     // [8192]
    float* out_mem    = out + OUT_F;                             // [8192]
    float* out_trace  = out + 2 * OUT_F;                         // [8192^2]
    float* out_refr   = out + 2 * OUT_F + (size_t)OUT_F * IN_F;  // [8192]

    snn_fused_kernel<<<OUT_F / 4, BLOCK, 0, stream>>>(
        (const f32x4*)x_in, syn, mem, thr, refr,
        (const f32x4*)trace,
        out_spikes, out_mem, out_refr,
        (f32x4*)out_trace);
}